// Round 1
// baseline (25.185 us; speedup 1.0000x reference)
//
#include <hip/hip_runtime.h>

// FractalHilbertTokenizer: images (32,3,1024,1024) f32 -> tokens (32,4096,48) f32 ++ levels (4096) = 6
// All leaves are 16x16 at level 6; gather top-left 4x4 of each, Hilbert order.

#define B_ 32
#define N_ 4096
#define C_ 3
#define MAIN_ (B_ * N_ * 12)   // one float4 row (b,n,c,i) per work item

__global__ __launch_bounds__(256) void fht_gather(const float* __restrict__ img,
                                                  float* __restrict__ out) {
    int idx = blockIdx.x * 256 + threadIdx.x;
    if (idx < MAIN_) {
        int b   = idx / (N_ * 12);
        int rem = idx - b * (N_ * 12);
        int n   = rem / 12;
        int t   = rem - n * 12;
        int c   = t >> 2;
        int i   = t & 3;

        // Hilbert leaf (y,x) from n: digit = visitation position, quad = ORDERS[l%4][digit].
        // ORDERS packed 2b/entry: {0,1,3,2}->0xB4 {2,0,1,3}->0xD2 {1,3,2,0}->0x2D {3,2,0,1}->0x4B
        const unsigned ordp0 = 0xB4u, ordp1 = 0xD2u, ordp2 = 0x2Du, ordp3 = 0x4Bu;
        int y = 0, x = 0;
#pragma unroll
        for (int l = 0; l < 6; ++l) {
            unsigned p = (l & 3) == 0 ? ordp0 : (l & 3) == 1 ? ordp1 : (l & 3) == 2 ? ordp2 : ordp3;
            int d = (n >> (2 * (5 - l))) & 3;
            int q = (p >> (2 * d)) & 3;
            int s = 512 >> l;
            y += (q >> 1) * s;
            x += (q & 1) * s;
        }

        const float4* src = reinterpret_cast<const float4*>(
            img + ((size_t)(b * C_ + c) * (1024u * 1024u) + (size_t)(y + i) * 1024u + (size_t)x));
        float4 v = *src;
        float4* dst = reinterpret_cast<float4*>(
            out + ((size_t)(b * N_ + n) * 48u + (size_t)(c * 16 + i * 4)));
        *dst = v;
    } else {
        int n = idx - MAIN_;
        if (n < N_) {
            out[(size_t)B_ * N_ * 48 + n] = 6.0f;   // levels, read back as fp32
        }
    }
}

extern "C" void kernel_launch(void* const* d_in, const int* in_sizes, int n_in,
                              void* d_out, int out_size, void* d_ws, size_t ws_size,
                              hipStream_t stream) {
    const float* img = (const float*)d_in[0];
    float* out = (float*)d_out;
    const int total = MAIN_ + N_;              // 1,576,960 = 6160 * 256 exactly
    const int blocks = (total + 255) / 256;
    fht_gather<<<blocks, 256, 0, stream>>>(img, out);
}

// Round 2
// 24.745 us; speedup vs baseline: 1.0178x; 1.0178x over previous
//
#include <hip/hip_runtime.h>

// FractalHilbertTokenizer: images (32,3,1024,1024) f32 -> tokens (32,4096,48) f32 ++ levels(4096)=6.
// All leaves are 16x16 at level 6; gather top-left 4x4 of each, Hilbert order.
// Strategy: stream-ordered reads. Block = (b, c, y-band); thread (i=tid&3, xl=tid>>2)
// reads float4 at row 16*yb+i, col 16*xl  (byte i*4096 + 64*xl within the band) ->
// each wave-load = 4 contiguous 1KB line-runs; block covers a linear 16KB region.
// Hilbert scatter lives on the write side: 4 lanes (i=0..3) store 64B contiguous per (n,c).

#define B_ 32
#define N_ 4096
#define C_ 3
#define MAIN_BLOCKS (B_ * C_ * 64)   // 6144
#define LVL_BLOCKS 16                // 4096 levels / 256

__global__ __launch_bounds__(256) void fht_gather2(const float* __restrict__ img,
                                                   float* __restrict__ out) {
    int bid = blockIdx.x;
    int tid = threadIdx.x;
    if (bid < MAIN_BLOCKS) {
        int yb = bid & 63;          // y-band index (leaf row), 0..63
        int bc = bid >> 6;          // b*3 + c
        int c  = bc % 3;
        int b  = bc / 3;
        int i  = tid & 3;           // row within 4x4 patch
        int xl = tid >> 2;          // leaf col index, 0..63

        // src: plane (b,c) is 1<<20 floats; y-band is 16 rows = 1<<14 floats.
        const float4* src = reinterpret_cast<const float4*>(img) +
                            ((size_t)bc << 18) + ((size_t)yb << 12);
        float4 v = src[i * 256 + xl * 4];   // row i, float4-col 4*xl (byte i*4096 + 64*xl)

        // Hilbert index n from (yl=yb, xl): digit d_l = INV_ORDER[l%4][q_l],
        // q_l = (ybit<<1)|xbit. INV packs (2b/entry, LSB-first by q):
        // inv{0,1,3,2}=0xB4  inv{2,0,1,3}={1,2,0,3}=0xC9  inv{1,3,2,0}={3,0,2,1}=0x63
        // inv{3,2,0,1}={2,3,1,0}=0x1E
        const unsigned invp0 = 0xB4u, invp1 = 0xC9u, invp2 = 0x63u, invp3 = 0x1Eu;
        int n = 0;
#pragma unroll
        for (int l = 0; l < 6; ++l) {
            unsigned p = (l & 3) == 0 ? invp0 : (l & 3) == 1 ? invp1
                       : (l & 3) == 2 ? invp2 : invp3;
            int sh = 5 - l;
            int q = (((yb >> sh) & 1) << 1) | ((xl >> sh) & 1);
            int d = (p >> (2 * q)) & 3;
            n |= d << (2 * sh);
        }

        // out token (b,n): 48 floats = 12 float4; c-block = 4 float4 (64B aligned); row i.
        float4* dst = reinterpret_cast<float4*>(out);
        dst[(size_t)(b * N_ + n) * 12 + c * 4 + i] = v;
    } else {
        int k = (bid - MAIN_BLOCKS) * 256 + tid;   // 0..4095
        out[(size_t)B_ * N_ * 48 + k] = 6.0f;      // levels
    }
}

extern "C" void kernel_launch(void* const* d_in, const int* in_sizes, int n_in,
                              void* d_out, int out_size, void* d_ws, size_t ws_size,
                              hipStream_t stream) {
    const float* img = (const float*)d_in[0];
    float* out = (float*)d_out;
    fht_gather2<<<MAIN_BLOCKS + LVL_BLOCKS, 256, 0, stream>>>(img, out);
}

// Round 3
// 23.646 us; speedup vs baseline: 1.0651x; 1.0465x over previous
//
#include <hip/hip_runtime.h>

// FractalHilbertTokenizer: images (32,3,1024,1024) f32 -> tokens (32,4096,48) f32 ++ levels(4096)=6.
// Both-streams-contiguous variant: block = (b, level-3 Hilbert tile) covering 8x8 leaves
// (128x128 px) whose 64 token indices are CONSECUTIVE (n in [t*64, t*64+64)).
// Read needed 16B chunks -> scatter into LDS token layout -> contiguous 12KB global write.

#define B_ 32
#define NT_ 64                   // level-3 tiles per image
#define MAIN_BLOCKS (B_ * NT_)   // 2048
#define LVL_BLOCKS 16

__global__ __launch_bounds__(256) void fht_gather3(const float* __restrict__ img,
                                                   float* __restrict__ out) {
    int bid = blockIdx.x;
    int tid = threadIdx.x;

    if (bid < MAIN_BLOCKS) {
        __shared__ float4 smem[768];           // 64 tokens x 48 floats = 12KB
        int t = bid & 63;                      // tile id (Hilbert levels 0..2)
        int b = bid >> 6;

        // Tile origin in tile units (0..7 per side) via forward ORDERS at l=0,1,2.
        // packs: {0,1,3,2}=0xB4 {2,0,1,3}=0xD2 {1,3,2,0}=0x2D   (HW-validated in R0)
        int Ty = 0, Tx = 0;
        {
            int d0 = (t >> 4) & 3, d1 = (t >> 2) & 3, d2 = t & 3;
            int q0 = (0xB4u >> (2 * d0)) & 3;
            int q1 = (0xD2u >> (2 * d1)) & 3;
            int q2 = (0x2Du >> (2 * d2)) & 3;
            Ty = ((q0 >> 1) << 2) | ((q1 >> 1) << 1) | (q2 >> 1);
            Tx = ((q0 & 1) << 2) | ((q1 & 1) << 1) | (q2 & 1);
        }
        int py = Ty << 7;                      // pixel origin of 128x128 tile
        int px = Tx << 7;

        // ---- read + LDS scatter: 768 float4 items, 3 per thread ----
#pragma unroll
        for (int k = 0; k < 3; ++k) {
            int r    = tid + (k << 8);
            int c    = r >> 8;                 // 0..2
            int rem  = r & 255;
            int band = rem >> 5;               // 0..7  (local leaf row)
            int i    = (rem >> 3) & 3;         // row within 4x4 patch
            int xl   = rem & 7;                // 0..7  (local leaf col)

            const float4* src = reinterpret_cast<const float4*>(img) +
                ((size_t)(b * 3 + c) << 18) +
                ((size_t)(py + band * 16 + i) << 8) +
                (px >> 2) + (xl << 2);
            float4 v = *src;

            // local Hilbert index from (band, xl): levels 3,4,5 -> l%4 = 3,0,1
            // inverse packs: invp3=0x1E invp0=0xB4 invp1=0xC9   (HW-validated in R2)
            int nl = 0;
            {
                int q, d;
                q = (((band >> 2) & 1) << 1) | ((xl >> 2) & 1);   // l=3
                d = (0x1Eu >> (2 * q)) & 3;  nl |= d << 4;
                q = (((band >> 1) & 1) << 1) | ((xl >> 1) & 1);   // l=4
                d = (0xB4u >> (2 * q)) & 3;  nl |= d << 2;
                q = ((band & 1) << 1) | (xl & 1);                 // l=5
                d = (0xC9u >> (2 * q)) & 3;  nl |= d;
            }
            smem[nl * 12 + c * 4 + i] = v;
        }
        __syncthreads();

        // ---- contiguous write: 12,288B per block, 1KB per wave-store ----
        float4* dst = reinterpret_cast<float4*>(out) + (size_t)bid * 768;
#pragma unroll
        for (int k = 0; k < 3; ++k) {
            int w = tid + (k << 8);
            dst[w] = smem[w];
        }
    } else {
        int n = (bid - MAIN_BLOCKS) * 256 + tid;        // 0..4095
        out[(size_t)B_ * 4096 * 48 + n] = 6.0f;         // levels
    }
}

extern "C" void kernel_launch(void* const* d_in, const int* in_sizes, int n_in,
                              void* d_out, int out_size, void* d_ws, size_t ws_size,
                              hipStream_t stream) {
    const float* img = (const float*)d_in[0];
    float* out = (float*)d_out;
    fht_gather3<<<MAIN_BLOCKS + LVL_BLOCKS, 256, 0, stream>>>(img, out);
}